// Round 10
// baseline (69.726 us; speedup 1.0000x reference)
//
#include <hip/hip_runtime.h>
#include <hip/hip_bf16.h>

#define D_IN  2048
#define D_OUT 2048
#define M_TOTAL 8192   // B*S = 4*2048

typedef __attribute__((ext_vector_type(4))) int   i32x4;   // i8 MFMA A/B/C frags
typedef __attribute__((ext_vector_type(4))) float f32x4;

typedef const __attribute__((address_space(1))) void gvoid_t;
typedef __attribute__((address_space(3))) void lvoid_t;

// ---------------------------------------------------------------------------
// Kernel 1: per-block partial sums of |w| in fp64 (deterministic, no atomics)
// ---------------------------------------------------------------------------
__global__ __launch_bounds__(256) void absum_kernel(const float* __restrict__ w,
                                                    double* __restrict__ partials) {
    const int n4 = (D_OUT * D_IN) / 4;          // 1,048,576 float4s
    int tid = blockIdx.x * 256 + threadIdx.x;
    int stride = gridDim.x * 256;
    double s = 0.0;
    for (int i = tid; i < n4; i += stride) {
        float4 v = reinterpret_cast<const float4*>(w)[i];
        s += (double)fabsf(v.x) + (double)fabsf(v.y) +
             (double)fabsf(v.z) + (double)fabsf(v.w);
    }
    for (int off = 32; off; off >>= 1) s += __shfl_xor(s, off, 64);
    __shared__ double ls[4];
    if ((threadIdx.x & 63) == 0) ls[threadIdx.x >> 6] = s;
    __syncthreads();
    if (threadIdx.x == 0)
        partials[blockIdx.x] = ls[0] + ls[1] + ls[2] + ls[3];
}

// ---------------------------------------------------------------------------
// Kernel 2 (merged): blocks 0..4095 = ternary quantize w -> int8 [N][K];
// blocks 4096..12287 = LayerNorm -> int8 [M][K] + per-row scale.
// ---------------------------------------------------------------------------
__device__ __forceinline__ unsigned pk4(float a, float b, float c, float d, float is) {
    int q0 = (int)rintf(a * is); q0 = min(127, max(-127, q0));
    int q1 = (int)rintf(b * is); q1 = min(127, max(-127, q1));
    int q2 = (int)rintf(c * is); q2 = min(127, max(-127, q2));
    int q3 = (int)rintf(d * is); q3 = min(127, max(-127, q3));
    return  (unsigned)(unsigned char)(char)q0        |
           ((unsigned)(unsigned char)(char)q1 << 8)  |
           ((unsigned)(unsigned char)(char)q2 << 16) |
           ((unsigned)(unsigned char)(char)q3 << 24);
}

__global__ __launch_bounds__(256) void quantln_kernel(const float* __restrict__ w,
                                                      const double* __restrict__ partials,
                                                      char* __restrict__ wq,
                                                      const float* __restrict__ x,
                                                      const float* __restrict__ gamma,
                                                      const float* __restrict__ beta,
                                                      char* __restrict__ xn,
                                                      float* __restrict__ s_row) {
    int t = threadIdx.x;
    if (blockIdx.x < 4096) {
        double s = partials[t] + partials[t + 256] + partials[t + 512] + partials[t + 768];
        for (int off = 32; off; off >>= 1) s += __shfl_xor(s, off, 64);
        __shared__ double ls[4];
        if ((t & 63) == 0) ls[t >> 6] = s;
        __syncthreads();
        double tot = ls[0] + ls[1] + ls[2] + ls[3];
        double inv = 1.0 / (tot / 4194304.0 + 1e-5);

        int i = blockIdx.x * 256 + t;
        float4 v = reinterpret_cast<const float4*>(w)[i];
        unsigned o = 0;
        #pragma unroll
        for (int j = 0; j < 4; ++j) {
            float wf = (j == 0) ? v.x : (j == 1) ? v.y : (j == 2) ? v.z : v.w;
            double r = rint((double)wf * inv);
            r = fmin(1.0, fmax(-1.0, r));
            int q = (int)r;
            o |= ((unsigned)(unsigned char)(char)q) << (8 * j);
        }
        reinterpret_cast<unsigned*>(wq)[i] = o;
    } else {
        int row = blockIdx.x - 4096;
        const float4* xr = reinterpret_cast<const float4*>(x + (size_t)row * D_IN);
        float4 v0 = xr[t];
        float4 v1 = xr[t + 256];
        float s  = v0.x + v0.y + v0.z + v0.w + v1.x + v1.y + v1.z + v1.w;
        float sq = v0.x*v0.x + v0.y*v0.y + v0.z*v0.z + v0.w*v0.w
                 + v1.x*v1.x + v1.y*v1.y + v1.z*v1.z + v1.w*v1.w;
        for (int off = 32; off; off >>= 1) {
            s  += __shfl_xor(s,  off, 64);
            sq += __shfl_xor(sq, off, 64);
        }
        __shared__ float lss[4], lqq[4], lmx[4];
        if ((t & 63) == 0) { lss[t >> 6] = s; lqq[t >> 6] = sq; }
        __syncthreads();
        s  = lss[0] + lss[1] + lss[2] + lss[3];
        sq = lqq[0] + lqq[1] + lqq[2] + lqq[3];
        float mu  = s * (1.0f / D_IN);
        float var = sq * (1.0f / D_IN) - mu * mu;
        float inv = rsqrtf(var + 1e-5f);

        const float4* g4 = reinterpret_cast<const float4*>(gamma);
        const float4* b4 = reinterpret_cast<const float4*>(beta);
        float4 g0 = g4[t], g1 = g4[t + 256];
        float4 b0 = b4[t], b1 = b4[t + 256];

        float a0 = (v0.x - mu) * inv * g0.x + b0.x;
        float a1 = (v0.y - mu) * inv * g0.y + b0.y;
        float a2 = (v0.z - mu) * inv * g0.z + b0.z;
        float a3 = (v0.w - mu) * inv * g0.w + b0.w;
        float a4 = (v1.x - mu) * inv * g1.x + b1.x;
        float a5 = (v1.y - mu) * inv * g1.y + b1.y;
        float a6 = (v1.z - mu) * inv * g1.z + b1.z;
        float a7 = (v1.w - mu) * inv * g1.w + b1.w;

        float mx = fmaxf(fmaxf(fmaxf(fabsf(a0), fabsf(a1)), fmaxf(fabsf(a2), fabsf(a3))),
                         fmaxf(fmaxf(fabsf(a4), fabsf(a5)), fmaxf(fabsf(a6), fabsf(a7))));
        for (int off = 32; off; off >>= 1) mx = fmaxf(mx, __shfl_xor(mx, off, 64));
        if ((t & 63) == 0) lmx[t >> 6] = mx;
        __syncthreads();
        float rowmax = fmaxf(fmaxf(lmx[0], lmx[1]), fmaxf(lmx[2], lmx[3]));

        float is = (rowmax > 0.0f) ? (127.0f / rowmax) : 0.0f;
        char* orow = xn + (size_t)row * D_IN;
        reinterpret_cast<unsigned*>(orow)[t]        = pk4(a0, a1, a2, a3, is);
        reinterpret_cast<unsigned*>(orow + 1024)[t] = pk4(a4, a5, a6, a7, is);
        if (t == 0) s_row[row] = rowmax * (1.0f / 127.0f);
    }
}

// ---------------------------------------------------------------------------
// Kernel 3: 256x256-tile 4-WAVE INT8 MFMA GEMM, wave-tile 128x128.
// R9 change: halve LDS read traffic. Per CU per K-tile: frag reads 64KB
// (4 waves x (128+128)x64B) vs 96KB with 8 waves of 128x64; + 32KB staged
// writes => LDS ~750-1000cy < MFMA 1306cy -> MFMA-bound with margin.
// Cost: acc 8x8 i32x4 = 256 VGPR -> 1 wave/SIMD (launch_bounds(256,1));
// latency hidden by ILP: 4-slot ring staging T+3 ahead (drain span ~3900cy),
// 1-phase frag read-ahead. Ring/swizzle geometry identical to R8 (proven),
// scaled to 4 loads/quantum: steady vmcnt(8), prologue vmcnt(16), tails 8/0/-.
// ---------------------------------------------------------------------------
#define NT (D_IN / 64)         // 32 K-tiles

__device__ __forceinline__ void stage_quantum(const char* __restrict__ gbase,
                                              int grow0, int kcol0,
                                              char* smem, int ldsbase, int tid) {
    const int lane = tid & 63;
    const int w    = tid >> 6;              // 0..3
    // inverse-swizzled global k-group: logical kg = phys(lane&3) ^ ((row>>1)&3)
    const int colx = (((lane & 3) ^ ((lane >> 3) & 3)) << 4);
    #pragma unroll
    for (int j = 0; j < 4; ++j) {
        const int c = w * 4 + j;            // 16 chunks of 16 rows (256 rows)
        const int r = c * 16 + (lane >> 2);
        const char* g = gbase + (size_t)(grow0 + r) * D_IN + kcol0 + colx;
        char* l = smem + ldsbase + c * 1024 + lane * 16;
        __builtin_amdgcn_global_load_lds((gvoid_t*)g, (lvoid_t*)l, 16, 0, 0);
    }
}

__device__ __forceinline__ i32x4 rdfrag(const char* smem, int off) {
    return *reinterpret_cast<const i32x4*>(smem + off);
}

template<int W>
__device__ __forceinline__ void vm_wait() {
    if constexpr (W == 8) {
        asm volatile("s_waitcnt vmcnt(8)" ::: "memory");
        __builtin_amdgcn_sched_barrier(0);
    } else if constexpr (W == 0) {
        asm volatile("s_waitcnt vmcnt(0)" ::: "memory");
        __builtin_amdgcn_sched_barrier(0);
    }
    // W == -1: no wait
}

#define MFMA32(ROW, AV, BV)                                                     \
    __builtin_amdgcn_sched_barrier(0);                                          \
    __builtin_amdgcn_s_setprio(1);                                              \
    _Pragma("unroll")                                                           \
    for (int m_ = 0; m_ < 4; ++m_)                                              \
        _Pragma("unroll")                                                       \
        for (int n_ = 0; n_ < 8; ++n_)                                          \
            acc[ROW + m_][n_] = __builtin_amdgcn_mfma_i32_16x16x64_i8(          \
                AV[m_], BV[n_], acc[ROW + m_][n_], 0, 0, 0);                    \
    __builtin_amdgcn_s_setprio(0);                                              \
    __builtin_amdgcn_sched_barrier(0);

template<int W, bool S, bool RD>
__device__ __forceinline__ void ktile(int T,
        const char* __restrict__ A, const char* __restrict__ B,
        int bm, int bn, char* smem, int tid, int aBase, int bBase,
        i32x4 (&aS0)[4], i32x4 (&aS1)[4], i32x4 (&bCur)[8], i32x4 (&bNxt)[8],
        i32x4 (&acc)[8][8]) {
    const int sA  = ((T & 3) << 14);
    const int sAn = (((T + 1) & 3) << 14);

    // ---- ph0: read A m4-7 (this tile); MFMA rows 0-3; counted wait; barrier
    #pragma unroll
    for (int f = 0; f < 4; ++f) aS1[f] = rdfrag(smem, sA + aBase + 4096 + f * 1024);
    MFMA32(0, aS0, bCur)
    vm_wait<W>();
    __builtin_amdgcn_s_barrier();

    // ---- ph1: read-ahead T+1 (A m0-3 + all B); stage T+3; MFMA rows 4-7
    if (RD) {
        #pragma unroll
        for (int f = 0; f < 4; ++f) aS0[f]  = rdfrag(smem, sAn + aBase + f * 1024);
        #pragma unroll
        for (int f = 0; f < 8; ++f) bNxt[f] = rdfrag(smem, 65536 + sAn + bBase + f * 1024);
    }
    if (S) {
        const int s3 = (((T + 3) & 3) << 14);
        stage_quantum(A, bm, (T + 3) * 64, smem, s3,         tid);
        stage_quantum(B, bn, (T + 3) * 64, smem, 65536 + s3, tid);
    }
    MFMA32(4, aS1, bCur)
    __builtin_amdgcn_s_barrier();
}

__global__ __launch_bounds__(256, 1) void gemm256_kernel(const char* __restrict__ A,
                                                         const char* __restrict__ B,
                                                         const float* __restrict__ bias,
                                                         const float* __restrict__ s_row,
                                                         float* __restrict__ C) {
    extern __shared__ char smem[];
    const int tid  = threadIdx.x;
    const int lane = tid & 63;
    const int wid  = tid >> 6;             // 0..3
    const int wm   = wid >> 1;             // 0..1
    const int wn   = wid & 1;              // 0..1

    // XCD-aware bijective swizzle (grid=256)
    const int orig = blockIdx.y * gridDim.x + blockIdx.x;   // 0..255
    const int swz  = (orig & 7) * 32 + (orig >> 3);
    const int bm   = (swz >> 3) * 256;
    const int bn   = (swz & 7) * 256;

    const int lr   = lane & 15;
    const int rdbase = lr * 64 + ((((lane >> 4) ^ ((lr >> 1) & 3))) << 4);
    const int aBase = wm * 8192 + rdbase;   // wm*128 rows * 64B
    const int bBase = wn * 8192 + rdbase;   // wn*128 rows * 64B

    i32x4 acc[8][8];
    #pragma unroll
    for (int m = 0; m < 8; ++m)
        #pragma unroll
        for (int n = 0; n < 8; ++n)
            acc[m][n] = (i32x4){0, 0, 0, 0};

    i32x4 aS0[4], aS1[4], bE[8], bO[8];

    // prologue: stage tiles 0,1,2 (24 loads/thread); drain tile0 -> vmcnt(16);
    // barrier; pre-read T=0 frags (A m0-3 + all B).
    stage_quantum(A, bm, 0,   smem, 0,             tid);
    stage_quantum(B, bn, 0,   smem, 65536,         tid);
    stage_quantum(A, bm, 64,  smem, 16384,         tid);
    stage_quantum(B, bn, 64,  smem, 65536 + 16384, tid);
    stage_quantum(A, bm, 128, smem, 32768,         tid);
    stage_quantum(B, bn, 128, smem, 65536 + 32768, tid);
    asm volatile("s_waitcnt vmcnt(16)" ::: "memory");
    __builtin_amdgcn_sched_barrier(0);
    __builtin_amdgcn_s_barrier();
    #pragma unroll
    for (int f = 0; f < 4; ++f) aS0[f] = rdfrag(smem, aBase + f * 1024);
    #pragma unroll
    for (int f = 0; f < 8; ++f) bE[f]  = rdfrag(smem, 65536 + bBase + f * 1024);
    __builtin_amdgcn_sched_barrier(0);

    for (int T = 0; T < 28; T += 2) {
        ktile<8, true, true>(T,     A, B, bm, bn, smem, tid, aBase, bBase, aS0, aS1, bE, bO, acc);
        ktile<8, true, true>(T + 1, A, B, bm, bn, smem, tid, aBase, bBase, aS0, aS1, bO, bE, acc);
    }
    ktile<8,  true,  true >(28, A, B, bm, bn, smem, tid, aBase, bBase, aS0, aS1, bE, bO, acc);
    ktile<8,  false, true >(29, A, B, bm, bn, smem, tid, aBase, bBase, aS0, aS1, bO, bE, acc);
    ktile<0,  false, true >(30, A, B, bm, bn, smem, tid, aBase, bBase, aS0, aS1, bE, bO, acc);
    ktile<-1, false, false>(31, A, B, bm, bn, smem, tid, aBase, bBase, aS0, aS1, bO, bE, acc);

    // ---- epilogue: out = s_row*acc + bias; per-wave LDS repack -> dwordx4 ----
    // Last tile reads slot 3 (A 48K..64K, B 112K..128K); eb at 0..33K: disjoint.
    const int EST = 528;                   // 128 floats + 16B pad
    char* eb = smem + wid * (16 * EST);    // 8448 B per wave
    const int C0 = bn + wn * 128;
    const int R0 = bm + wm * 128;
    const int rowsub = (lane >> 4) * 4;
    float bv[8];
    #pragma unroll
    for (int n = 0; n < 8; ++n) bv[n] = bias[C0 + n * 16 + lr];

    #pragma unroll
    for (int m = 0; m < 8; ++m) {
        float sr[4];
        #pragma unroll
        for (int i = 0; i < 4; ++i) sr[i] = s_row[R0 + m * 16 + rowsub + i];
        #pragma unroll
        for (int n = 0; n < 8; ++n)
            #pragma unroll
            for (int i = 0; i < 4; ++i)
                *reinterpret_cast<float*>(eb + (rowsub + i) * EST + (n * 16 + lr) * 4)
                    = (float)acc[m][n][i] * sr[i] + bv[n];
        #pragma unroll
        for (int q = 0; q < 8; ++q) {
            const int row = q * 2 + (lane >> 5);
            const int col = (lane & 31) * 4;
            f32x4 v = *reinterpret_cast<const f32x4*>(eb + row * EST + col * 4);
            *reinterpret_cast<f32x4*>(&C[(size_t)(R0 + m * 16 + row) * D_OUT + C0 + col]) = v;
        }
    }
}

// ---------------------------------------------------------------------------
extern "C" void kernel_launch(void* const* d_in, const int* in_sizes, int n_in,
                              void* d_out, int out_size, void* d_ws, size_t ws_size,
                              hipStream_t stream) {
    const float* x     = (const float*)d_in[0];   // [4,2048,2048]
    const float* w     = (const float*)d_in[1];   // [2048,2048]
    const float* bias  = (const float*)d_in[2];   // [2048]
    const float* gamma = (const float*)d_in[3];   // [2048]
    const float* beta  = (const float*)d_in[4];   // [2048]
    float* out = (float*)d_out;

    char* ws = (char*)d_ws;
    double* partials = (double*)ws;                         // 8KB
    float*  s_row    = (float*)(ws + 8192);                 // 32KB (8192 rows)
    char*   wq       = ws + 65536;                          // 4MB  i8 [N][K]
    char*   xn       = ws + 65536 + 4ull * 1024 * 1024;     // 16MB i8 [M][K]

    hipFuncSetAttribute(reinterpret_cast<const void*>(gemm256_kernel),
                        hipFuncAttributeMaxDynamicSharedMemorySize, 131072);

    absum_kernel   <<<1024, 256, 0, stream>>>(w, partials);
    quantln_kernel <<<12288, 256, 0, stream>>>(w, partials, wq, x, gamma, beta, xn, s_row);
    gemm256_kernel <<<dim3(8, 32), 256, 131072, stream>>>(xn, wq, bias, s_row, out);
}

// Round 11
// 64.195 us; speedup vs baseline: 1.0862x; 1.0862x over previous
//
#include <hip/hip_runtime.h>
#include <hip/hip_bf16.h>

#define D_IN  2048
#define D_OUT 2048
#define M_TOTAL 8192   // B*S = 4*2048

typedef __attribute__((ext_vector_type(4))) int   i32x4;   // i8 MFMA A/B/C frags
typedef __attribute__((ext_vector_type(4))) float f32x4;

typedef const __attribute__((address_space(1))) void gvoid_t;
typedef __attribute__((address_space(3))) void lvoid_t;

// ---------------------------------------------------------------------------
// Kernel 1: per-block partial sums of |w| in fp64 (deterministic, no atomics)
// ---------------------------------------------------------------------------
__global__ __launch_bounds__(256) void absum_kernel(const float* __restrict__ w,
                                                    double* __restrict__ partials) {
    const int n4 = (D_OUT * D_IN) / 4;          // 1,048,576 float4s
    int tid = blockIdx.x * 256 + threadIdx.x;
    int stride = gridDim.x * 256;
    double s = 0.0;
    for (int i = tid; i < n4; i += stride) {
        float4 v = reinterpret_cast<const float4*>(w)[i];
        s += (double)fabsf(v.x) + (double)fabsf(v.y) +
             (double)fabsf(v.z) + (double)fabsf(v.w);
    }
    for (int off = 32; off; off >>= 1) s += __shfl_xor(s, off, 64);
    __shared__ double ls[4];
    if ((threadIdx.x & 63) == 0) ls[threadIdx.x >> 6] = s;
    __syncthreads();
    if (threadIdx.x == 0)
        partials[blockIdx.x] = ls[0] + ls[1] + ls[2] + ls[3];
}

// ---------------------------------------------------------------------------
// Kernel 2 (merged): blocks 0..4095 = ternary quantize w -> int8 [N][K];
// blocks 4096..12287 = LayerNorm -> int8 [M][K] + per-row scale.
// ---------------------------------------------------------------------------
__device__ __forceinline__ unsigned pk4(float a, float b, float c, float d, float is) {
    int q0 = (int)rintf(a * is); q0 = min(127, max(-127, q0));
    int q1 = (int)rintf(b * is); q1 = min(127, max(-127, q1));
    int q2 = (int)rintf(c * is); q2 = min(127, max(-127, q2));
    int q3 = (int)rintf(d * is); q3 = min(127, max(-127, q3));
    return  (unsigned)(unsigned char)(char)q0        |
           ((unsigned)(unsigned char)(char)q1 << 8)  |
           ((unsigned)(unsigned char)(char)q2 << 16) |
           ((unsigned)(unsigned char)(char)q3 << 24);
}

__global__ __launch_bounds__(256) void quantln_kernel(const float* __restrict__ w,
                                                      const double* __restrict__ partials,
                                                      char* __restrict__ wq,
                                                      const float* __restrict__ x,
                                                      const float* __restrict__ gamma,
                                                      const float* __restrict__ beta,
                                                      char* __restrict__ xn,
                                                      float* __restrict__ s_row) {
    int t = threadIdx.x;
    if (blockIdx.x < 4096) {
        double s = partials[t] + partials[t + 256] + partials[t + 512] + partials[t + 768];
        for (int off = 32; off; off >>= 1) s += __shfl_xor(s, off, 64);
        __shared__ double ls[4];
        if ((t & 63) == 0) ls[t >> 6] = s;
        __syncthreads();
        double tot = ls[0] + ls[1] + ls[2] + ls[3];
        double inv = 1.0 / (tot / 4194304.0 + 1e-5);

        int i = blockIdx.x * 256 + t;
        float4 v = reinterpret_cast<const float4*>(w)[i];
        unsigned o = 0;
        #pragma unroll
        for (int j = 0; j < 4; ++j) {
            float wf = (j == 0) ? v.x : (j == 1) ? v.y : (j == 2) ? v.z : v.w;
            double r = rint((double)wf * inv);
            r = fmin(1.0, fmax(-1.0, r));
            int q = (int)r;
            o |= ((unsigned)(unsigned char)(char)q) << (8 * j);
        }
        reinterpret_cast<unsigned*>(wq)[i] = o;
    } else {
        int row = blockIdx.x - 4096;
        const float4* xr = reinterpret_cast<const float4*>(x + (size_t)row * D_IN);
        float4 v0 = xr[t];
        float4 v1 = xr[t + 256];
        float s  = v0.x + v0.y + v0.z + v0.w + v1.x + v1.y + v1.z + v1.w;
        float sq = v0.x*v0.x + v0.y*v0.y + v0.z*v0.z + v0.w*v0.w
                 + v1.x*v1.x + v1.y*v1.y + v1.z*v1.z + v1.w*v1.w;
        for (int off = 32; off; off >>= 1) {
            s  += __shfl_xor(s,  off, 64);
            sq += __shfl_xor(sq, off, 64);
        }
        __shared__ float lss[4], lqq[4], lmx[4];
        if ((t & 63) == 0) { lss[t >> 6] = s; lqq[t >> 6] = sq; }
        __syncthreads();
        s  = lss[0] + lss[1] + lss[2] + lss[3];
        sq = lqq[0] + lqq[1] + lqq[2] + lqq[3];
        float mu  = s * (1.0f / D_IN);
        float var = sq * (1.0f / D_IN) - mu * mu;
        float inv = rsqrtf(var + 1e-5f);

        const float4* g4 = reinterpret_cast<const float4*>(gamma);
        const float4* b4 = reinterpret_cast<const float4*>(beta);
        float4 g0 = g4[t], g1 = g4[t + 256];
        float4 b0 = b4[t], b1 = b4[t + 256];

        float a0 = (v0.x - mu) * inv * g0.x + b0.x;
        float a1 = (v0.y - mu) * inv * g0.y + b0.y;
        float a2 = (v0.z - mu) * inv * g0.z + b0.z;
        float a3 = (v0.w - mu) * inv * g0.w + b0.w;
        float a4 = (v1.x - mu) * inv * g1.x + b1.x;
        float a5 = (v1.y - mu) * inv * g1.y + b1.y;
        float a6 = (v1.z - mu) * inv * g1.z + b1.z;
        float a7 = (v1.w - mu) * inv * g1.w + b1.w;

        float mx = fmaxf(fmaxf(fmaxf(fabsf(a0), fabsf(a1)), fmaxf(fabsf(a2), fabsf(a3))),
                         fmaxf(fmaxf(fabsf(a4), fabsf(a5)), fmaxf(fabsf(a6), fabsf(a7))));
        for (int off = 32; off; off >>= 1) mx = fmaxf(mx, __shfl_xor(mx, off, 64));
        if ((t & 63) == 0) lmx[t >> 6] = mx;
        __syncthreads();
        float rowmax = fmaxf(fmaxf(lmx[0], lmx[1]), fmaxf(lmx[2], lmx[3]));

        float is = (rowmax > 0.0f) ? (127.0f / rowmax) : 0.0f;
        char* orow = xn + (size_t)row * D_IN;
        reinterpret_cast<unsigned*>(orow)[t]        = pk4(a0, a1, a2, a3, is);
        reinterpret_cast<unsigned*>(orow + 1024)[t] = pk4(a4, a5, a6, a7, is);
        if (t == 0) s_row[row] = rowmax * (1.0f / 127.0f);
    }
}

// ---------------------------------------------------------------------------
// Kernel 3: 256x256-tile 8-wave INT8 MFMA GEMM (R8 structure, reverted).
// R10 A/B: REMOVE sched_barrier(0)/setprio pinning around MFMA clusters —
// let the compiler interleave ds_read/gload_lds into the MFMA stream (m141:
// pinning cost 40%+; m97: compiler's fine-grained lgkmcnt is near-optimal).
// Barriers are asm volatile + "memory" clobber (orders ds/global ops at the
// compiler level across the barrier — needed now that the full fences are
// gone). sched_barrier(0) retained ONLY after counted vmcnt waits (rule 18).
// Schedule, 4-slot ring, swizzle, waits: byte-identical to R8's ledger.
// ---------------------------------------------------------------------------
#define BM 256
#define BN 256
#define NT (D_IN / 64)         // 32 K-tiles

__device__ __forceinline__ void stage_quantum(const char* __restrict__ gbase,
                                              int grow0, int kcol0,
                                              char* smem, int ldsbase, int tid) {
    const int lane = tid & 63;
    const int w    = tid >> 6;
    // inverse-swizzled global k-group: logical kg = phys(lane&3) ^ ((row>>1)&3),
    // row = lane>>2 -> (row>>1)&3 = (lane>>3)&3
    const int colx = (((lane & 3) ^ ((lane >> 3) & 3)) << 4);   // bytes
    #pragma unroll
    for (int j = 0; j < 2; ++j) {
        const int c = w * 2 + j;                    // 1KB chunk id, 0..15 (16 rows each)
        const int r = c * 16 + (lane >> 2);         // row within 256
        const char* g = gbase + (size_t)(grow0 + r) * D_IN + kcol0 + colx;
        char* l = smem + ldsbase + c * 1024 + lane * 16;   // linear dest
        __builtin_amdgcn_global_load_lds((gvoid_t*)g, (lvoid_t*)l, 16, 0, 0);
    }
}

__device__ __forceinline__ i32x4 rdfrag(const char* smem, int off) {
    return *reinterpret_cast<const i32x4*>(smem + off);
}

template<int W>
__device__ __forceinline__ void vm_wait() {
    if constexpr (W == 4) {
        asm volatile("s_waitcnt vmcnt(4)" ::: "memory");
        __builtin_amdgcn_sched_barrier(0);
    } else if constexpr (W == 0) {
        asm volatile("s_waitcnt vmcnt(0)" ::: "memory");
        __builtin_amdgcn_sched_barrier(0);
    }
    // W == -1: no wait
}

// Unpinned MFMA cluster: no sched_barrier, no setprio — compiler is free to
// interleave the phase's ds_reads / gload_lds with these MFMAs.
#define MFMA16(ROW, AV, BV)                                                     \
    _Pragma("unroll")                                                           \
    for (int m_ = 0; m_ < 4; ++m_)                                              \
        _Pragma("unroll")                                                       \
        for (int n_ = 0; n_ < 4; ++n_)                                          \
            acc[ROW + m_][n_] = __builtin_amdgcn_mfma_i32_16x16x64_i8(          \
                AV[m_], BV[n_], acc[ROW + m_][n_], 0, 0, 0);

template<int W, bool S, bool RD>
__device__ __forceinline__ void ktile(int T,
        const char* __restrict__ A, const char* __restrict__ B,
        int bm, int bn, char* smem, int tid, int aBase, int bBase,
        i32x4 (&aS0)[4], i32x4 (&aS1)[4], i32x4 (&bCur)[4], i32x4 (&bNxt)[4],
        i32x4 (&acc)[8][4]) {
    const int sA  = ((T & 3) << 14);
    const int sAn = (((T + 1) & 3) << 14);

    // ---- ph0 ----
    #pragma unroll
    for (int f = 0; f < 4; ++f) aS1[f] = rdfrag(smem, sA + aBase + 4096 + f * 1024);
    MFMA16(0, aS0, bCur)
    vm_wait<W>();
    asm volatile("s_barrier" ::: "memory");

    // ---- ph1 ----
    if (RD) {
        #pragma unroll
        for (int f = 0; f < 4; ++f) aS0[f]  = rdfrag(smem, sAn + aBase + f * 1024);
        #pragma unroll
        for (int f = 0; f < 4; ++f) bNxt[f] = rdfrag(smem, 65536 + sAn + bBase + f * 1024);
    }
    if (S) {
        const int s3 = (((T + 3) & 3) << 14);
        stage_quantum(A, bm, (T + 3) * 64, smem, s3,         tid);
        stage_quantum(B, bn, (T + 3) * 64, smem, 65536 + s3, tid);
    }
    MFMA16(4, aS1, bCur)
    asm volatile("s_barrier" ::: "memory");
}

__global__ __launch_bounds__(512, 2) void gemm256_kernel(const char* __restrict__ A,
                                                         const char* __restrict__ B,
                                                         const float* __restrict__ bias,
                                                         const float* __restrict__ s_row,
                                                         float* __restrict__ C) {
    extern __shared__ char smem[];
    const int tid  = threadIdx.x;
    const int lane = tid & 63;
    const int wid  = tid >> 6;
    const int wm   = wid >> 2;           // 0..1
    const int wn   = wid & 3;            // 0..3

    // XCD-aware bijective swizzle (grid=256): each XCD owns 4 contiguous
    // M-panels (L2-resident A)
    const int orig = blockIdx.y * gridDim.x + blockIdx.x;   // 0..255
    const int swz  = (orig & 7) * 32 + (orig >> 3);
    const int bm   = (swz >> 3) * BM;
    const int bn   = (swz & 7) * BN;

    const int lr   = lane & 15;
    // conflict-free swizzled ds_read base: phys kg = (lane>>4) ^ ((lr>>1)&3)
    const int rdbase = lr * 64 + ((((lane >> 4) ^ ((lr >> 1) & 3))) << 4);
    const int aBase = wm * 8192 + rdbase;     // wm*128 rows * 64B
    const int bBase = wn * 4096 + rdbase;     // wn*64 rows * 64B

    i32x4 acc[8][4];
    #pragma unroll
    for (int m = 0; m < 8; ++m)
        #pragma unroll
        for (int n = 0; n < 4; ++n)
            acc[m][n] = (i32x4){0, 0, 0, 0};

    i32x4 aS0[4], aS1[4], bE[4], bO[4];

    // prologue: stage tiles 0,1,2 (12 loads/thread); drain tile0 -> vmcnt(8);
    // barrier; pre-read ph0(T=0) frags.
    stage_quantum(A, bm, 0,   smem, 0,             tid);
    stage_quantum(B, bn, 0,   smem, 65536,         tid);
    stage_quantum(A, bm, 64,  smem, 16384,         tid);
    stage_quantum(B, bn, 64,  smem, 65536 + 16384, tid);
    stage_quantum(A, bm, 128, smem, 32768,         tid);
    stage_quantum(B, bn, 128, smem, 65536 + 32768, tid);
    asm volatile("s_waitcnt vmcnt(8)" ::: "memory");
    __builtin_amdgcn_sched_barrier(0);
    asm volatile("s_barrier" ::: "memory");
    #pragma unroll
    for (int f = 0; f < 4; ++f) aS0[f] = rdfrag(smem, aBase + f * 1024);
    #pragma unroll
    for (int f = 0; f < 4; ++f) bE[f]  = rdfrag(smem, 65536 + bBase + f * 1024);

    // even tiles use bE as current, odd tiles bO. Stage while T+3 <= 31.
    for (int T = 0; T < 28; T += 2) {
        ktile<4, true, true>(T,     A, B, bm, bn, smem, tid, aBase, bBase, aS0, aS1, bE, bO, acc);
        ktile<4, true, true>(T + 1, A, B, bm, bn, smem, tid, aBase, bBase, aS0, aS1, bO, bE, acc);
    }
    ktile<4,  true,  true >(28, A, B, bm, bn, smem, tid, aBase, bBase, aS0, aS1, bE, bO, acc);
    ktile<4,  false, true >(29, A, B, bm, bn, smem, tid, aBase, bBase, aS0, aS1, bO, bE, acc);
    ktile<0,  false, true >(30, A, B, bm, bn, smem, tid, aBase, bBase, aS0, aS1, bE, bO, acc);
    ktile<-1, false, false>(31, A, B, bm, bn, smem, tid, aBase, bBase, aS0, aS1, bO, bE, acc);

    // ---- epilogue: out = s_row[row]*acc + bias[col]; LDS repack -> dwordx4 ----
    const int EST = 272;                       // row stride bytes (anti-conflict pad)
    char* eb = smem + wid * (16 * EST);        // 4352 B per wave
    const int C0 = bn + wn * 64;
    const int R0 = bm + wm * 128;
    const int rowsub = (lane >> 4) * 4;
    float bv[4];
    #pragma unroll
    for (int n = 0; n < 4; ++n) bv[n] = bias[C0 + n * 16 + lr];

    #pragma unroll
    for (int m = 0; m < 8; ++m) {
        float sr[4];
        #pragma unroll
        for (int i = 0; i < 4; ++i) sr[i] = s_row[R0 + m * 16 + rowsub + i];
        #pragma unroll
        for (int n = 0; n < 4; ++n)
            #pragma unroll
            for (int i = 0; i < 4; ++i)
                *reinterpret_cast<float*>(eb + (rowsub + i) * EST + (n * 16 + lr) * 4)
                    = (float)acc[m][n][i] * sr[i] + bv[n];
        #pragma unroll
        for (int q = 0; q < 4; ++q) {
            const int row = (lane >> 4) + q * 4;
            f32x4 v = *reinterpret_cast<const f32x4*>(eb + row * EST + lr * 16);
            *reinterpret_cast<f32x4*>(&C[(size_t)(R0 + m * 16 + row) * D_OUT + C0 + lr * 4]) = v;
        }
    }
}

// ---------------------------------------------------------------------------
extern "C" void kernel_launch(void* const* d_in, const int* in_sizes, int n_in,
                              void* d_out, int out_size, void* d_ws, size_t ws_size,
                              hipStream_t stream) {
    const float* x     = (const float*)d_in[0];   // [4,2048,2048]
    const float* w     = (const float*)d_in[1];   // [2048,2048]
    const float* bias  = (const float*)d_in[2];   // [2048]
    const float* gamma = (const float*)d_in[3];   // [2048]
    const float* beta  = (const float*)d_in[4];   // [2048]
    float* out = (float*)d_out;

    char* ws = (char*)d_ws;
    double* partials = (double*)ws;                         // 8KB
    float*  s_row    = (float*)(ws + 8192);                 // 32KB (8192 rows)
    char*   wq       = ws + 65536;                          // 4MB  i8 [N][K]
    char*   xn       = ws + 65536 + 4ull * 1024 * 1024;     // 16MB i8 [M][K]

    hipFuncSetAttribute(reinterpret_cast<const void*>(gemm256_kernel),
                        hipFuncAttributeMaxDynamicSharedMemorySize, 131072);

    absum_kernel   <<<1024, 256, 0, stream>>>(w, partials);
    quantln_kernel <<<12288, 256, 0, stream>>>(w, partials, wq, x, gamma, beta, xn, s_row);
    gemm256_kernel <<<dim3(D_OUT / BN, M_TOTAL / BM), 512, 131072, stream>>>(xn, wq, bias, s_row, out);
}

// Round 12
// 63.235 us; speedup vs baseline: 1.1026x; 1.0152x over previous
//
#include <hip/hip_runtime.h>
#include <hip/hip_bf16.h>

#define D_IN  2048
#define D_OUT 2048
#define M_TOTAL 8192   // B*S = 4*2048

typedef __attribute__((ext_vector_type(4))) int   i32x4;   // i8 MFMA A/B/C frags
typedef __attribute__((ext_vector_type(4))) float f32x4;

typedef const __attribute__((address_space(1))) void gvoid_t;
typedef __attribute__((address_space(3))) void lvoid_t;

// ---------------------------------------------------------------------------
// Kernel 1: per-block partial sums of |w| in fp64 (deterministic, no atomics)
// ---------------------------------------------------------------------------
__global__ __launch_bounds__(256) void absum_kernel(const float* __restrict__ w,
                                                    double* __restrict__ partials) {
    const int n4 = (D_OUT * D_IN) / 4;          // 1,048,576 float4s
    int tid = blockIdx.x * 256 + threadIdx.x;
    int stride = gridDim.x * 256;
    double s = 0.0;
    for (int i = tid; i < n4; i += stride) {
        float4 v = reinterpret_cast<const float4*>(w)[i];
        s += (double)fabsf(v.x) + (double)fabsf(v.y) +
             (double)fabsf(v.z) + (double)fabsf(v.w);
    }
    for (int off = 32; off; off >>= 1) s += __shfl_xor(s, off, 64);
    __shared__ double ls[4];
    if ((threadIdx.x & 63) == 0) ls[threadIdx.x >> 6] = s;
    __syncthreads();
    if (threadIdx.x == 0)
        partials[blockIdx.x] = ls[0] + ls[1] + ls[2] + ls[3];
}

// ---------------------------------------------------------------------------
// Kernel 2 (merged): blocks 0..4095 = ternary quantize w -> int8 [N][K];
// blocks 4096..12287 = LayerNorm -> int8 [M][K] + per-row scale.
// ---------------------------------------------------------------------------
__device__ __forceinline__ unsigned pk4(float a, float b, float c, float d, float is) {
    int q0 = (int)rintf(a * is); q0 = min(127, max(-127, q0));
    int q1 = (int)rintf(b * is); q1 = min(127, max(-127, q1));
    int q2 = (int)rintf(c * is); q2 = min(127, max(-127, q2));
    int q3 = (int)rintf(d * is); q3 = min(127, max(-127, q3));
    return  (unsigned)(unsigned char)(char)q0        |
           ((unsigned)(unsigned char)(char)q1 << 8)  |
           ((unsigned)(unsigned char)(char)q2 << 16) |
           ((unsigned)(unsigned char)(char)q3 << 24);
}

__global__ __launch_bounds__(256) void quantln_kernel(const float* __restrict__ w,
                                                      const double* __restrict__ partials,
                                                      char* __restrict__ wq,
                                                      const float* __restrict__ x,
                                                      const float* __restrict__ gamma,
                                                      const float* __restrict__ beta,
                                                      char* __restrict__ xn,
                                                      float* __restrict__ s_row) {
    int t = threadIdx.x;
    if (blockIdx.x < 4096) {
        double s = partials[t] + partials[t + 256] + partials[t + 512] + partials[t + 768];
        for (int off = 32; off; off >>= 1) s += __shfl_xor(s, off, 64);
        __shared__ double ls[4];
        if ((t & 63) == 0) ls[t >> 6] = s;
        __syncthreads();
        double tot = ls[0] + ls[1] + ls[2] + ls[3];
        double inv = 1.0 / (tot / 4194304.0 + 1e-5);

        int i = blockIdx.x * 256 + t;
        float4 v = reinterpret_cast<const float4*>(w)[i];
        unsigned o = 0;
        #pragma unroll
        for (int j = 0; j < 4; ++j) {
            float wf = (j == 0) ? v.x : (j == 1) ? v.y : (j == 2) ? v.z : v.w;
            double r = rint((double)wf * inv);
            r = fmin(1.0, fmax(-1.0, r));
            int q = (int)r;
            o |= ((unsigned)(unsigned char)(char)q) << (8 * j);
        }
        reinterpret_cast<unsigned*>(wq)[i] = o;
    } else {
        int row = blockIdx.x - 4096;
        const float4* xr = reinterpret_cast<const float4*>(x + (size_t)row * D_IN);
        float4 v0 = xr[t];
        float4 v1 = xr[t + 256];
        float s  = v0.x + v0.y + v0.z + v0.w + v1.x + v1.y + v1.z + v1.w;
        float sq = v0.x*v0.x + v0.y*v0.y + v0.z*v0.z + v0.w*v0.w
                 + v1.x*v1.x + v1.y*v1.y + v1.z*v1.z + v1.w*v1.w;
        for (int off = 32; off; off >>= 1) {
            s  += __shfl_xor(s,  off, 64);
            sq += __shfl_xor(sq, off, 64);
        }
        __shared__ float lss[4], lqq[4], lmx[4];
        if ((t & 63) == 0) { lss[t >> 6] = s; lqq[t >> 6] = sq; }
        __syncthreads();
        s  = lss[0] + lss[1] + lss[2] + lss[3];
        sq = lqq[0] + lqq[1] + lqq[2] + lqq[3];
        float mu  = s * (1.0f / D_IN);
        float var = sq * (1.0f / D_IN) - mu * mu;
        float inv = rsqrtf(var + 1e-5f);

        const float4* g4 = reinterpret_cast<const float4*>(gamma);
        const float4* b4 = reinterpret_cast<const float4*>(beta);
        float4 g0 = g4[t], g1 = g4[t + 256];
        float4 b0 = b4[t], b1 = b4[t + 256];

        float a0 = (v0.x - mu) * inv * g0.x + b0.x;
        float a1 = (v0.y - mu) * inv * g0.y + b0.y;
        float a2 = (v0.z - mu) * inv * g0.z + b0.z;
        float a3 = (v0.w - mu) * inv * g0.w + b0.w;
        float a4 = (v1.x - mu) * inv * g1.x + b1.x;
        float a5 = (v1.y - mu) * inv * g1.y + b1.y;
        float a6 = (v1.z - mu) * inv * g1.z + b1.z;
        float a7 = (v1.w - mu) * inv * g1.w + b1.w;

        float mx = fmaxf(fmaxf(fmaxf(fabsf(a0), fabsf(a1)), fmaxf(fabsf(a2), fabsf(a3))),
                         fmaxf(fmaxf(fabsf(a4), fabsf(a5)), fmaxf(fabsf(a6), fabsf(a7))));
        for (int off = 32; off; off >>= 1) mx = fmaxf(mx, __shfl_xor(mx, off, 64));
        if ((t & 63) == 0) lmx[t >> 6] = mx;
        __syncthreads();
        float rowmax = fmaxf(fmaxf(lmx[0], lmx[1]), fmaxf(lmx[2], lmx[3]));

        float is = (rowmax > 0.0f) ? (127.0f / rowmax) : 0.0f;
        char* orow = xn + (size_t)row * D_IN;
        reinterpret_cast<unsigned*>(orow)[t]        = pk4(a0, a1, a2, a3, is);
        reinterpret_cast<unsigned*>(orow + 1024)[t] = pk4(a4, a5, a6, a7, is);
        if (t == 0) s_row[row] = rowmax * (1.0f / 127.0f);
    }
}

// ---------------------------------------------------------------------------
// Kernel 3: 256x256-tile 8-wave INT8 MFMA GEMM.
// R11 change: ONE barrier per K-tile (at ph0-end, after the counted vmcnt).
// The ph1-end barrier is redundant per the re-derived ledger:
//  RAW: slot T+1 (staged T-2.ph1) drained by T.ph0-end vmcnt(4)+barrier,
//   covering both T.ph1's read-ahead and T+1.ph0's aS1 reads.
//  WAR: T.ph1 stages slot (T-1)&3; a slow wave's last reads of that slot
//   (T-1.ph0, lgkm-forced before its T-1.ph1 cluster) precede the shared
//   T.ph0-end barrier that the staging wave has passed.
// A FINAL barrier before the epilogue is now required (eb repack region
// overlaps slots 0-2 that a slow wave may still be reading in tiles 30/31).
// Unpinned MFMA clusters (R10 win) retained; ring/swizzle/waits unchanged.
// ---------------------------------------------------------------------------
#define BM 256
#define BN 256
#define NT (D_IN / 64)         // 32 K-tiles

__device__ __forceinline__ void stage_quantum(const char* __restrict__ gbase,
                                              int grow0, int kcol0,
                                              char* smem, int ldsbase, int tid) {
    const int lane = tid & 63;
    const int w    = tid >> 6;
    // inverse-swizzled global k-group: logical kg = phys(lane&3) ^ ((row>>1)&3),
    // row = lane>>2 -> (row>>1)&3 = (lane>>3)&3
    const int colx = (((lane & 3) ^ ((lane >> 3) & 3)) << 4);   // bytes
    #pragma unroll
    for (int j = 0; j < 2; ++j) {
        const int c = w * 2 + j;                    // 1KB chunk id, 0..15 (16 rows each)
        const int r = c * 16 + (lane >> 2);         // row within 256
        const char* g = gbase + (size_t)(grow0 + r) * D_IN + kcol0 + colx;
        char* l = smem + ldsbase + c * 1024 + lane * 16;   // linear dest
        __builtin_amdgcn_global_load_lds((gvoid_t*)g, (lvoid_t*)l, 16, 0, 0);
    }
}

__device__ __forceinline__ i32x4 rdfrag(const char* smem, int off) {
    return *reinterpret_cast<const i32x4*>(smem + off);
}

template<int W>
__device__ __forceinline__ void vm_wait() {
    if constexpr (W == 4) {
        asm volatile("s_waitcnt vmcnt(4)" ::: "memory");
        __builtin_amdgcn_sched_barrier(0);
    } else if constexpr (W == 0) {
        asm volatile("s_waitcnt vmcnt(0)" ::: "memory");
        __builtin_amdgcn_sched_barrier(0);
    }
    // W == -1: no wait
}

// Unpinned MFMA cluster: compiler freely interleaves ds_read/gload_lds.
#define MFMA16(ROW, AV, BV)                                                     \
    _Pragma("unroll")                                                           \
    for (int m_ = 0; m_ < 4; ++m_)                                              \
        _Pragma("unroll")                                                       \
        for (int n_ = 0; n_ < 4; ++n_)                                          \
            acc[ROW + m_][n_] = __builtin_amdgcn_mfma_i32_16x16x64_i8(          \
                AV[m_], BV[n_], acc[ROW + m_][n_], 0, 0, 0);

template<int W, bool S, bool RD>
__device__ __forceinline__ void ktile(int T,
        const char* __restrict__ A, const char* __restrict__ B,
        int bm, int bn, char* smem, int tid, int aBase, int bBase,
        i32x4 (&aS0)[4], i32x4 (&aS1)[4], i32x4 (&bCur)[4], i32x4 (&bNxt)[4],
        i32x4 (&acc)[8][4]) {
    const int sA  = ((T & 3) << 14);
    const int sAn = (((T + 1) & 3) << 14);

    // ---- ph0: read own aS1; MFMA rows 0-3; counted wait; the ONE barrier ----
    #pragma unroll
    for (int f = 0; f < 4; ++f) aS1[f] = rdfrag(smem, sA + aBase + 4096 + f * 1024);
    MFMA16(0, aS0, bCur)
    vm_wait<W>();
    asm volatile("s_barrier" ::: "memory");

    // ---- ph1: read-ahead T+1; stage T+3; MFMA rows 4-7; NO barrier ----
    if (RD) {
        #pragma unroll
        for (int f = 0; f < 4; ++f) aS0[f]  = rdfrag(smem, sAn + aBase + f * 1024);
        #pragma unroll
        for (int f = 0; f < 4; ++f) bNxt[f] = rdfrag(smem, 65536 + sAn + bBase + f * 1024);
    }
    if (S) {
        const int s3 = (((T + 3) & 3) << 14);
        stage_quantum(A, bm, (T + 3) * 64, smem, s3,         tid);
        stage_quantum(B, bn, (T + 3) * 64, smem, 65536 + s3, tid);
    }
    MFMA16(4, aS1, bCur)
    // no barrier — ph1 and next tile's ph0 form one unfenced stretch
}

__global__ __launch_bounds__(512, 2) void gemm256_kernel(const char* __restrict__ A,
                                                         const char* __restrict__ B,
                                                         const float* __restrict__ bias,
                                                         const float* __restrict__ s_row,
                                                         float* __restrict__ C) {
    extern __shared__ char smem[];
    const int tid  = threadIdx.x;
    const int lane = tid & 63;
    const int wid  = tid >> 6;
    const int wm   = wid >> 2;           // 0..1
    const int wn   = wid & 3;            // 0..3

    // XCD-aware bijective swizzle (grid=256): each XCD owns 4 contiguous
    // M-panels (L2-resident A)
    const int orig = blockIdx.y * gridDim.x + blockIdx.x;   // 0..255
    const int swz  = (orig & 7) * 32 + (orig >> 3);
    const int bm   = (swz >> 3) * BM;
    const int bn   = (swz & 7) * BN;

    const int lr   = lane & 15;
    // conflict-free swizzled ds_read base: phys kg = (lane>>4) ^ ((lr>>1)&3)
    const int rdbase = lr * 64 + ((((lane >> 4) ^ ((lr >> 1) & 3))) << 4);
    const int aBase = wm * 8192 + rdbase;     // wm*128 rows * 64B
    const int bBase = wn * 4096 + rdbase;     // wn*64 rows * 64B

    i32x4 acc[8][4];
    #pragma unroll
    for (int m = 0; m < 8; ++m)
        #pragma unroll
        for (int n = 0; n < 4; ++n)
            acc[m][n] = (i32x4){0, 0, 0, 0};

    i32x4 aS0[4], aS1[4], bE[4], bO[4];

    // prologue: stage tiles 0,1,2 (12 loads/thread); drain tile0 -> vmcnt(8);
    // barrier; pre-read ph0(T=0) frags.
    stage_quantum(A, bm, 0,   smem, 0,             tid);
    stage_quantum(B, bn, 0,   smem, 65536,         tid);
    stage_quantum(A, bm, 64,  smem, 16384,         tid);
    stage_quantum(B, bn, 64,  smem, 65536 + 16384, tid);
    stage_quantum(A, bm, 128, smem, 32768,         tid);
    stage_quantum(B, bn, 128, smem, 65536 + 32768, tid);
    asm volatile("s_waitcnt vmcnt(8)" ::: "memory");
    __builtin_amdgcn_sched_barrier(0);
    asm volatile("s_barrier" ::: "memory");
    #pragma unroll
    for (int f = 0; f < 4; ++f) aS0[f] = rdfrag(smem, aBase + f * 1024);
    #pragma unroll
    for (int f = 0; f < 4; ++f) bE[f]  = rdfrag(smem, 65536 + bBase + f * 1024);

    // even tiles use bE as current, odd tiles bO. Stage while T+3 <= 31.
    for (int T = 0; T < 28; T += 2) {
        ktile<4, true, true>(T,     A, B, bm, bn, smem, tid, aBase, bBase, aS0, aS1, bE, bO, acc);
        ktile<4, true, true>(T + 1, A, B, bm, bn, smem, tid, aBase, bBase, aS0, aS1, bO, bE, acc);
    }
    ktile<4,  true,  true >(28, A, B, bm, bn, smem, tid, aBase, bBase, aS0, aS1, bE, bO, acc);
    ktile<4,  false, true >(29, A, B, bm, bn, smem, tid, aBase, bBase, aS0, aS1, bO, bE, acc);
    ktile<0,  false, true >(30, A, B, bm, bn, smem, tid, aBase, bBase, aS0, aS1, bE, bO, acc);
    ktile<-1, false, false>(31, A, B, bm, bn, smem, tid, aBase, bBase, aS0, aS1, bO, bE, acc);

    // Final barrier: epilogue's eb region (slots 0-2 bytes) may be read by
    // slow waves still in tiles 30/31 without this.
    asm volatile("s_barrier" ::: "memory");

    // ---- epilogue: out = s_row[row]*acc + bias[col]; LDS repack -> dwordx4 ----
    const int EST = 272;                       // row stride bytes (anti-conflict pad)
    char* eb = smem + wid * (16 * EST);        // 4352 B per wave
    const int C0 = bn + wn * 64;
    const int R0 = bm + wm * 128;
    const int rowsub = (lane >> 4) * 4;
    float bv[4];
    #pragma unroll
    for (int n = 0; n < 4; ++n) bv[n] = bias[C0 + n * 16 + lr];

    #pragma unroll
    for (int m = 0; m < 8; ++m) {
        float sr[4];
        #pragma unroll
        for (int i = 0; i < 4; ++i) sr[i] = s_row[R0 + m * 16 + rowsub + i];
        #pragma unroll
        for (int n = 0; n < 4; ++n)
            #pragma unroll
            for (int i = 0; i < 4; ++i)
                *reinterpret_cast<float*>(eb + (rowsub + i) * EST + (n * 16 + lr) * 4)
                    = (float)acc[m][n][i] * sr[i] + bv[n];
        #pragma unroll
        for (int q = 0; q < 4; ++q) {
            const int row = (lane >> 4) + q * 4;
            f32x4 v = *reinterpret_cast<const f32x4*>(eb + row * EST + lr * 16);
            *reinterpret_cast<f32x4*>(&C[(size_t)(R0 + m * 16 + row) * D_OUT + C0 + lr * 4]) = v;
        }
    }
}

// ---------------------------------------------------------------------------
extern "C" void kernel_launch(void* const* d_in, const int* in_sizes, int n_in,
                              void* d_out, int out_size, void* d_ws, size_t ws_size,
                              hipStream_t stream) {
    const float* x     = (const float*)d_in[0];   // [4,2048,2048]
    const float* w     = (const float*)d_in[1];   // [2048,2048]
    const float* bias  = (const float*)d_in[2];   // [2048]
    const float* gamma = (const float*)d_in[3];   // [2048]
    const float* beta  = (const float*)d_in[4];   // [2048]
    float* out = (float*)d_out;

    char* ws = (char*)d_ws;
    double* partials = (double*)ws;                         // 8KB
    float*  s_row    = (float*)(ws + 8192);                 // 32KB (8192 rows)
    char*   wq       = ws + 65536;                          // 4MB  i8 [N][K]
    char*   xn       = ws + 65536 + 4ull * 1024 * 1024;     // 16MB i8 [M][K]

    hipFuncSetAttribute(reinterpret_cast<const void*>(gemm256_kernel),
                        hipFuncAttributeMaxDynamicSharedMemorySize, 131072);

    absum_kernel   <<<1024, 256, 0, stream>>>(w, partials);
    quantln_kernel <<<12288, 256, 0, stream>>>(w, partials, wq, x, gamma, beta, xn, s_row);
    gemm256_kernel <<<dim3(D_OUT / BN, M_TOTAL / BM), 512, 131072, stream>>>(xn, wq, bias, s_row, out);
}